// Round 1
// baseline (1137.972 us; speedup 1.0000x reference)
//
#include <hip/hip_runtime.h>
#include <hip/hip_bf16.h>

// Problem constants
// B=16, N=512, H=512, G=8, L=16, D=64, SCALE = 512^-0.5

typedef __attribute__((ext_vector_type(8))) __bf16 bf16x8;
typedef __attribute__((ext_vector_type(4))) float f32x4;

static __device__ __forceinline__ f32x4 mfma16(bf16x8 a, bf16x8 b, f32x4 c) {
    return __builtin_amdgcn_mfma_f32_16x16x32_bf16(a, b, c, 0, 0, 0);
}

static __device__ __forceinline__ ushort f2b(float f) {
    __hip_bfloat16 h = __float2bfloat16(f);
    return __builtin_bit_cast(ushort, h);
}

// ---------------------------------------------------------------------------
// prep: x -> bf16; transpose+convert weights to col-major bf16 (BT[c][k])
// ---------------------------------------------------------------------------
__global__ void prep_kernel(const float* __restrict__ x, const float* __restrict__ Wq,
                            const float* __restrict__ Wk, const float* __restrict__ Wv,
                            const float* __restrict__ Wout,
                            ushort* __restrict__ xb, ushort* __restrict__ WqT,
                            ushort* __restrict__ WkT, ushort* __restrict__ WvT,
                            ushort* __restrict__ WoutT)
{
    size_t i = (size_t)blockIdx.x * blockDim.x + threadIdx.x;
    const size_t XN = 8192UL * 512UL;
    if (i < XN) { xb[i] = f2b(x[i]); return; }
    i -= XN;
    if (i < 262144) { size_t c = i >> 9, k = i & 511; WqT[i] = f2b(Wq[k * 512 + c]); return; }
    i -= 262144;
    if (i < 262144) { size_t c = i >> 9, k = i & 511; WkT[i] = f2b(Wk[k * 512 + c]); return; }
    i -= 262144;
    if (i < 524288) { size_t c = i >> 9, k = i & 511; WvT[i] = f2b(Wv[k * 1024 + c]); return; }
    i -= 524288;
    if (i < 524288) { size_t c = i >> 10, k = i & 1023; WoutT[i] = f2b(Wout[k * 512 + c]); return; }
}

// ---------------------------------------------------------------------------
// generic bf16 MFMA GEMM: C[r,c] = sum_k A[r,k] * BT[c,k]
// block = 4 waves, block tile 16 rows x 64 cols, each wave one 16x16 tile
// mode 0: bf16 out natural; mode 2: +bias, scatter to v_t[b][l][d][m];
// mode 1: f32 out natural
// ---------------------------------------------------------------------------
__global__ __launch_bounds__(256) void gemm16(
    const ushort* __restrict__ A, const ushort* __restrict__ BT,
    const float* __restrict__ bias, void* __restrict__ out,
    int K, int Cols, int mode)
{
    int r0 = blockIdx.x * 16;
    int wv = threadIdx.x >> 6, lane = threadIdx.x & 63;
    int lo = lane & 15, hi = lane >> 4;
    int c0 = blockIdx.y * 64 + wv * 16;
    const ushort* arow = A + (size_t)(r0 + lo) * K;
    const ushort* brow = BT + (size_t)(c0 + lo) * K;
    f32x4 acc = {0.f, 0.f, 0.f, 0.f};
    for (int kk = 0; kk < K; kk += 32) {
        bf16x8 af = *(const bf16x8*)(arow + kk + hi * 8);
        bf16x8 bf = *(const bf16x8*)(brow + kk + hi * 8);
        acc = mfma16(af, bf, acc);
    }
    if (mode == 0) {
        ushort* C = (ushort*)out;
#pragma unroll
        for (int r = 0; r < 4; r++)
            C[(size_t)(r0 + hi * 4 + r) * Cols + c0 + lo] = f2b(acc[r]);
    } else if (mode == 2) {
        int c = c0 + lo;
        float bs = bias[c];
        int l = c >> 6, d = c & 63;
        ushort* vt = (ushort*)out;
#pragma unroll
        for (int r = 0; r < 4; r++) {
            int row = r0 + hi * 4 + r;
            int b = row >> 9, m = row & 511;
            vt[(((size_t)b * 16 + l) * 64 + d) * 512 + m] = f2b(acc[r] + bs);
        }
    } else {
        float* C = (float*)out;
#pragma unroll
        for (int r = 0; r < 4; r++)
            C[(size_t)(r0 + hi * 4 + r) * Cols + c0 + lo] = acc[r];
    }
}

// ---------------------------------------------------------------------------
// fused attention: scores (MFMA) -> noise+MLP+prior+softmax(L) -> PV (MFMA)
// grid (b=16, ntile=32), 256 threads (4 waves). n-tile=16, m-tile=32.
// wave w computes scores for g = 2w,2w+1 and owns output heads l = 4w..4w+3.
// ---------------------------------------------------------------------------
__global__ __launch_bounds__(256) void attn_kernel(
    const ushort* __restrict__ qb, const ushort* __restrict__ kb,
    const ushort* __restrict__ vt, const float* __restrict__ eps,
    const float* __restrict__ prior, const float* __restrict__ sigma,
    const float* __restrict__ Wp1, const float* __restrict__ bp1,
    const float* __restrict__ Wp2, const float* __restrict__ bp2,
    ushort* __restrict__ ob)
{
    __shared__ float gk[16 * 32 * 9];      // [n][m][9]  (pad 9 kills bank conflicts)
    __shared__ ushort als[16 * 16 * 40];   // [l][n][40] (stride 40 -> 2-way only)
    __shared__ float wp1[128], wp2[256], wb1[16], wb2[16], wsg[8];

    int b = blockIdx.x, n0 = blockIdx.y * 16;
    int tid = threadIdx.x, wv = tid >> 6, lane = tid & 63;
    int lo = lane & 15, hi = lane >> 4;

    if (tid < 128) wp1[tid] = Wp1[tid];
    wp2[tid] = Wp2[tid];
    if (tid < 16) { wb1[tid] = bp1[tid]; wb2[tid] = bp2[tid]; }
    if (tid < 8) { float s = sigma[tid]; wsg[tid] = s * s; }

    // Q fragments held in registers for the whole block
    bf16x8 qf[2][2];
#pragma unroll
    for (int gi = 0; gi < 2; gi++)
#pragma unroll
        for (int kc = 0; kc < 2; kc++)
            qf[gi][kc] = *(const bf16x8*)(qb + (size_t)(b * 512 + n0 + lo) * 512
                                          + (2 * wv + gi) * 64 + kc * 32 + hi * 8);

    f32x4 oacc[4][4];
#pragma unroll
    for (int i = 0; i < 4; i++)
#pragma unroll
        for (int j = 0; j < 4; j++)
            oacc[i][j] = (f32x4){0.f, 0.f, 0.f, 0.f};

    for (int m0 = 0; m0 < 512; m0 += 32) {
        // ---- scores: g_k[n, m, g] for this wave's two g heads
#pragma unroll
        for (int gi = 0; gi < 2; gi++) {
            int g = 2 * wv + gi;
#pragma unroll
            for (int mh = 0; mh < 2; mh++) {
                f32x4 c = {0.f, 0.f, 0.f, 0.f};
#pragma unroll
                for (int kc = 0; kc < 2; kc++) {
                    bf16x8 kf = *(const bf16x8*)(kb + (size_t)(b * 512 + m0 + mh * 16 + lo) * 512
                                                 + g * 64 + kc * 32 + hi * 8);
                    c = mfma16(qf[gi][kc], kf, c);
                }
#pragma unroll
                for (int r = 0; r < 4; r++)
                    gk[((4 * hi + r) * 32 + mh * 16 + lo) * 9 + g] = c[r];
            }
        }
        __syncthreads();

        // ---- noise + MLP(mish) + prior + softmax over L; 2 positions/thread
#pragma unroll
        for (int pp = 0; pp < 2; pp++) {
            int p = tid + pp * 256;
            int n = p >> 5, m = p & 31;
            float av[8];
            bool pad = true;
#pragma unroll
            for (int g = 0; g < 8; g++) {
                float v = gk[(n * 32 + m) * 9 + g];
                pad = pad && (v == 0.0f);
                av[g] = v;
            }
            ushort* arow = als + n * 40 + m;   // stride 640 per l
            if (pad) {
#pragma unroll
                for (int l = 0; l < 16; l++) arow[l * 640] = (ushort)0;
            } else {
                const float* erow = eps + (((size_t)b * 512 + n0 + n) * 512 + (m0 + m)) * 8;
#pragma unroll
                for (int g = 0; g < 8; g++) av[g] += wsg[g] * erow[g];
                float hmi[16];
#pragma unroll
                for (int l = 0; l < 16; l++) {
                    float t = wb1[l];
#pragma unroll
                    for (int g = 0; g < 8; g++) t += av[g] * wp1[g * 16 + l];
                    float sp = (t > 15.f) ? t : __logf(1.f + __expf(t));
                    float e2 = __expf(-2.f * sp);
                    hmi[l] = t * (1.f - e2) / (1.f + e2);   // mish
                }
                const float* pr = prior + ((size_t)(b * 16) * 512 + (n0 + n)) * 512 + (m0 + m);
                float o16[16];
                float mx = -1e30f;
#pragma unroll
                for (int l2 = 0; l2 < 16; l2++) {
                    float t = wb2[l2];
#pragma unroll
                    for (int l = 0; l < 16; l++) t += hmi[l] * wp2[l * 16 + l2];
                    t = t * 0.044194173824159216f + pr[(size_t)l2 * 262144];
                    o16[l2] = t;
                    mx = fmaxf(mx, t);
                }
                float se[16], ssum = 0.f;
#pragma unroll
                for (int l = 0; l < 16; l++) { se[l] = __expf(o16[l] - mx); ssum += se[l]; }
                float inv = 1.f / ssum;
#pragma unroll
                for (int l = 0; l < 16; l++) arow[l * 640] = f2b(se[l] * inv);
            }
        }
        __syncthreads();

        // ---- PV: o[n,l,d] += a[n,m,l] * v[m,l,d], this wave's 4 l heads
#pragma unroll
        for (int li = 0; li < 4; li++) {
            int l = 4 * wv + li;
            bf16x8 af = *(const bf16x8*)(als + l * 640 + lo * 40 + hi * 8);
#pragma unroll
            for (int dt = 0; dt < 4; dt++) {
                bf16x8 vf = *(const bf16x8*)(vt + (((size_t)b * 16 + l) * 64 + dt * 16 + lo) * 512
                                             + m0 + hi * 8);
                oacc[li][dt] = mfma16(af, vf, oacc[li][dt]);
            }
        }
        __syncthreads();
    }

    // ---- write O as (b, n, l*64+d) bf16
#pragma unroll
    for (int li = 0; li < 4; li++)
#pragma unroll
        for (int dt = 0; dt < 4; dt++)
#pragma unroll
            for (int r = 0; r < 4; r++)
                ob[(size_t)(b * 512 + n0 + 4 * hi + r) * 1024
                   + (4 * wv + li) * 64 + dt * 16 + lo] = f2b(oacc[li][dt][r]);
}

// ---------------------------------------------------------------------------
extern "C" void kernel_launch(void* const* d_in, const int* in_sizes, int n_in,
                              void* d_out, int out_size, void* d_ws, size_t ws_size,
                              hipStream_t stream)
{
    const float* x     = (const float*)d_in[0];
    const float* prior = (const float*)d_in[1];
    const float* eps   = (const float*)d_in[2];
    const float* Wq    = (const float*)d_in[3];
    const float* Wk    = (const float*)d_in[4];
    const float* Wv    = (const float*)d_in[5];
    const float* bv    = (const float*)d_in[6];
    const float* sigma = (const float*)d_in[7];
    const float* Wp1   = (const float*)d_in[8];
    const float* bp1   = (const float*)d_in[9];
    const float* Wp2   = (const float*)d_in[10];
    const float* bp2   = (const float*)d_in[11];
    const float* Wout  = (const float*)d_in[12];

    char* ws = (char*)d_ws;
    ushort* xb    = (ushort*)(ws);                  // 8 MB  : x bf16 (8192x512)
    ushort* qb    = (ushort*)(ws + (8UL  << 20));   // 8 MB  : q bf16 (8192x512)
    ushort* kb    = (ushort*)(ws + (16UL << 20));   // 8 MB  : k bf16 (8192x512)
    ushort* vt    = (ushort*)(ws + (24UL << 20));   // 16 MB : v_t bf16 [b][l][d][m]
    ushort* ob    = (ushort*)(ws + (40UL << 20));   // 16 MB : o bf16 (8192x1024)
    ushort* WqT   = (ushort*)(ws + (56UL << 20));   // 512 KB
    ushort* WkT   = (ushort*)(ws + (57UL << 20));   // 512 KB
    ushort* WvT   = (ushort*)(ws + (58UL << 20));   // 1 MB
    ushort* WoutT = (ushort*)(ws + (60UL << 20));   // 1 MB

    const size_t prep_total = 4194304UL + 262144 + 262144 + 524288 + 524288;
    prep_kernel<<<dim3((unsigned)((prep_total + 255) / 256)), 256, 0, stream>>>(
        x, Wq, Wk, Wv, Wout, xb, WqT, WkT, WvT, WoutT);

    gemm16<<<dim3(512, 8),  256, 0, stream>>>(xb, WqT, nullptr, qb,  512, 512,  0);
    gemm16<<<dim3(512, 8),  256, 0, stream>>>(xb, WkT, nullptr, kb,  512, 512,  0);
    gemm16<<<dim3(512, 16), 256, 0, stream>>>(xb, WvT, bv,      vt,  512, 1024, 2);

    attn_kernel<<<dim3(16, 32), 256, 0, stream>>>(qb, kb, vt, eps, prior, sigma,
                                                  Wp1, bp1, Wp2, bp2, ob);

    gemm16<<<dim3(512, 8), 256, 0, stream>>>(ob, WoutT, nullptr, d_out, 1024, 512, 1);
}